// Round 16
// baseline (220.344 us; speedup 1.0000x reference)
//
#include <hip/hip_runtime.h>

typedef __bf16 bf16x8 __attribute__((ext_vector_type(8)));
typedef __bf16 bf16x4 __attribute__((ext_vector_type(4)));
typedef float f32x4 __attribute__((ext_vector_type(4)));
typedef float f32x16 __attribute__((ext_vector_type(16)));
typedef unsigned short u16x4 __attribute__((ext_vector_type(4)));
typedef unsigned short u16x8 __attribute__((ext_vector_type(8)));

#define LQS 2048
#define LKS 2048
#define DMODEL 1024
#define NH 16
#define HDIM 64
#define NSPLIT 4
#define KVB 128
#define NT 4  // KV tiles per block = (LKS/NSPLIT)/KVB

#if __has_builtin(__builtin_amdgcn_exp2f)
#define EXP2(x) __builtin_amdgcn_exp2f(x)
#else
#define EXP2(x) exp2f(x)
#endif

#if __has_builtin(__builtin_amdgcn_mfma_f32_32x32x8bf16_1k)
#define HAS_K8 1
#else
#define HAS_K8 0
#endif

__device__ __forceinline__ unsigned short f2bf(float f) {
  union { float f; unsigned int u; } v; v.f = f;
  unsigned int r = v.u + 0x7FFFu + ((v.u >> 16) & 1u);
  return (unsigned short)(r >> 16);
}

// pack two f32 -> one u32 of two bf16
__device__ __forceinline__ unsigned int pk2(float a, float b) {
  __bf16 lo = (__bf16)a, hi = (__bf16)b;
  unsigned short ul = __builtin_bit_cast(unsigned short, lo);
  unsigned short uh = __builtin_bit_cast(unsigned short, hi);
  return (unsigned)ul | ((unsigned)uh << 16);
}

// async global->LDS, 16B per lane; LDS dest is wave-uniform base + lane*16
#define ASYNC_CP16(gp, lp)                                                     \
  __builtin_amdgcn_global_load_lds(                                            \
      (const __attribute__((address_space(1))) unsigned int*)(gp),             \
      (__attribute__((address_space(3))) unsigned int*)(lp), 16, 0, 0)

// ---------------- fused f32 -> bf16 conversion (all 6 tensors, 1 launch) -----
// Extra block (blockIdx == 4096) zeroes the attn completion counters each call
// (graph replays re-run this first node -> deterministic counter state).
struct CvtDesc { const float* src; unsigned short* dst; float scl; unsigned int nchunk; };
struct CvtBatch { CvtDesc d[6]; };

__global__ __launch_bounds__(256)
void cvt_all_k(CvtBatch cb, int* __restrict__ cnt) {
  if (blockIdx.x == 4096) {
    if (threadIdx.x < 256) cnt[threadIdx.x] = 0;
    return;
  }
  unsigned int c = blockIdx.x * 256 + threadIdx.x;  // 8-elem chunk id
#pragma unroll
  for (int s = 0; s < 6; ++s) {
    if (c < cb.d[s].nchunk) {
      const float* src = cb.d[s].src + (size_t)c * 8;
      float4 a = *(const float4*)(src);
      float4 b = *(const float4*)(src + 4);
      const float scl = cb.d[s].scl;
      u16x8 r;
      r[0] = f2bf(a.x * scl); r[1] = f2bf(a.y * scl);
      r[2] = f2bf(a.z * scl); r[3] = f2bf(a.w * scl);
      r[4] = f2bf(b.x * scl); r[5] = f2bf(b.y * scl);
      r[6] = f2bf(b.z * scl); r[7] = f2bf(b.w * scl);
      *(u16x8*)(cb.d[s].dst + (size_t)c * 8) = r;
      return;
    }
    c -= cb.d[s].nchunk;
  }
}

// ---------------- GEMM: C[M,N] = A[M,K](bf16) * B[N,K]^T(bf16) ----------------
// Templated tile BM x BN, BK=32, 4 waves (2x2); 2-phase pipeline; uniform
// blocks/CU (QKV 3/CU, O-proj 2/CU). T2 both-sides chunk swizzle retained.
struct GemmDesc { const unsigned short* A; const unsigned short* B; void* C; int ldc; int transC; };
struct GemmBatch3 { GemmDesc d[3]; };

template<int BM, int BN, bool F32OUT>
__global__ __launch_bounds__(256)
void gemm_bt(GemmBatch3 gb, int K) {
  constexpr int MFR = BM / 32;
  constexpr int NFR = BN / 32;
  const GemmDesc g = gb.d[blockIdx.z];
  __shared__ __align__(16) unsigned short sA[2][BM * 32];
  __shared__ __align__(16) unsigned short sB[2][BN * 32];
  const int tid = threadIdx.x;
  const int w = tid >> 6, l = tid & 63;
  const int wr = w >> 1, wc = w & 1;
  const int lr = l & 15, lk = (l >> 4) * 8;
  const unsigned short* Ab = g.A + (size_t)(blockIdx.y * BM) * K;
  const unsigned short* Bb = g.B + (size_t)(blockIdx.x * BN) * K;
  const int srow = w * 16 + (l >> 2);
  const int scol = (((l & 3) ^ (srow & 3)) * 8);

  auto stage = [&](int buf, int k0) {
#pragma unroll
    for (int ia = 0; ia < BM / 64; ++ia)
      ASYNC_CP16(Ab + (size_t)(ia * 64 + srow) * K + k0 + scol,
                 sA[buf] + ia * 2048 + w * 512);
#pragma unroll
    for (int ib = 0; ib < BN / 64; ++ib)
      ASYNC_CP16(Bb + (size_t)(ib * 64 + srow) * K + k0 + scol,
                 sB[buf] + ib * 2048 + w * 512);
  };

  f32x4 acc[MFR][NFR] = {};
  stage(0, 0);
  __syncthreads();
  int cur = 0;
  for (int k0 = 0; k0 < K; k0 += 32) {
    if (k0 + 32 < K) stage(cur ^ 1, k0 + 32);
    bf16x8 af[MFR], bfr[NFR];
#pragma unroll
    for (int m = 0; m < MFR; ++m) {
      const int Ar = wr * (BM / 2) + m * 16 + lr;
      af[m] = *(const bf16x8*)(sA[cur] + Ar * 32 + (((l >> 4) ^ (Ar & 3)) * 8));
    }
#pragma unroll
    for (int n = 0; n < NFR; ++n) {
      const int Br = wc * (BN / 2) + n * 16 + lr;
      bfr[n] = *(const bf16x8*)(sB[cur] + Br * 32 + (((l >> 4) ^ (Br & 3)) * 8));
    }
#pragma unroll
    for (int m = 0; m < MFR; ++m)
#pragma unroll
      for (int n = 0; n < NFR; ++n)
        acc[m][n] = __builtin_amdgcn_mfma_f32_16x16x32_bf16(af[m], bfr[n], acc[m][n], 0, 0, 0);
    __syncthreads();
    cur ^= 1;
  }
  // C/D layout: col = lane&15, row = (lane>>4)*4 + r  (m89-verified)
  const int r0 = blockIdx.y * BM + wr * (BM / 2) + (l >> 4) * 4;
  const int c0 = blockIdx.x * BN + wc * (BN / 2) + lr;
  if (g.transC) {
#pragma unroll
    for (int m = 0; m < MFR; ++m)
#pragma unroll
      for (int n = 0; n < NFR; ++n) {
        u16x4 v;
#pragma unroll
        for (int r = 0; r < 4; ++r) v[r] = f2bf(acc[m][n][r]);
        *(u16x4*)((unsigned short*)g.C + (size_t)(c0 + n * 16) * g.ldc + r0 + m * 16) = v;
      }
  } else {
#pragma unroll
    for (int m = 0; m < MFR; ++m)
#pragma unroll
      for (int n = 0; n < NFR; ++n)
#pragma unroll
        for (int r = 0; r < 4; ++r) {
          size_t idx = (size_t)(r0 + m * 16 + r) * g.ldc + c0 + n * 16;
          if (F32OUT) ((float*)g.C)[idx] = acc[m][n][r];
          else        ((unsigned short*)g.C)[idx] = f2bf(acc[m][n][r]);
        }
  }
}

// ---------------- flash attention, fixed-max (exact; log2-domain scores) -----
// 32x32x16 swapped QK^T; P in registers; PV + rowsum via mfma_32x32x8bf16_1k.
// KVB=128 / NT=4: halves barrier+stage events vs KVB=64 (per-output LDS/MFMA/
// VALU unchanged); proven round-11 2-phase 2-buffer __syncthreads pipeline.
// T1 XCD decode kept. FUSED COMBINE: last z-block per (qt,h) (same-XCD L2 by
// construction: xcd = (h+16z)%8 = h%8) sums the 4 partials and writes ctx.
__global__ __launch_bounds__(256)
void attn_k(const unsigned short* __restrict__ Q, const unsigned short* __restrict__ K,
            const unsigned short* __restrict__ Vt,
            __bf16* pacc, float* plsum, int* __restrict__ cnt, __bf16* ctx) {
  __shared__ __align__(16) __bf16 sK[2][KVB * 64];  // 16KB per buf
  __shared__ __align__(16) __bf16 sV[2][64 * KVB];  // 16KB per buf
  __shared__ int lastf;
  // T1 decode: combo c (= h + 16z) pinned to XCD c%8
  const int b = blockIdx.x;
  const int xcd = b & 7, rr = b >> 3;
  const int qt = rr & 15, chi = rr >> 4;
  const int c = xcd + 8 * chi;
  const int h = c & 15, z = c >> 4;
  const int tid = threadIdx.x;
  const int w = tid >> 6, l = tid & 63;
  const int lq = l & 31;   // q-column lane (C col = lane&31)
  const int hi = l >> 5;   // k-half selector
  const int qw0 = qt * 128 + w * 32;

  // Q as B-frag: qf[t] = Q[qw0+lq][h*64 + t*16 + hi*8 .. +7]
  bf16x8 qf[4];
#pragma unroll
  for (int t = 0; t < 4; ++t)
    qf[t] = *(const bf16x8*)(Q + (size_t)(qw0 + lq) * DMODEL + h * HDIM + t * 16 + hi * 8);

  f32x16 accO[2] = {};   // O[q rows via C-layout][d = db*32 + lq]
#if HAS_K8
  f32x16 accsum = {};    // rowsum via ones-B MFMA
  bf16x4 onesv;
#pragma unroll
  for (int j = 0; j < 4; ++j) onesv[j] = (__bf16)1.0f;
#else
  float lrun = 0.f;
#endif

  const int kt0 = z * (LKS / NSPLIT);

  // Stage one KVB x 64 K-tile (rows=keys, 128B/row) + 64 x KVB V-tile
  // (rows=d, 256B/row); XOR swizzle ^((row&7)<<4) pre-applied to the GLOBAL
  // source column (LDS dest linear, rule #21).
#define STAGE(B, KT)                                                           \
  do {                                                                         \
    _Pragma("unroll")                                                          \
    for (int i_ = 0; i_ < 4; ++i_) {                                           \
      const int krow_ = w * 32 + i_ * 8 + (l >> 3);                            \
      const int ksc_ = ((l & 7) * 16) ^ ((krow_ & 7) << 4);                    \
      ASYNC_CP16(K + (size_t)((KT) + krow_) * DMODEL + h * HDIM + ksc_ / 2,    \
                 (char*)(&sK[B][0]) + w * 4096 + i_ * 1024);                   \
      const int vrow_ = w * 16 + i_ * 4 + (l >> 4);                            \
      const int vsc_ = ((l & 15) * 16) ^ ((vrow_ & 7) << 4);                   \
      ASYNC_CP16(Vt + (size_t)(h * HDIM + vrow_) * LKS + (KT) + vsc_ / 2,      \
                 (char*)(&sV[B][0]) + w * 4096 + i_ * 1024);                   \
    }                                                                          \
  } while (0)

  STAGE(0, kt0);
  __syncthreads();  // tile 0 resident (syncthreads drains vmcnt)
  int cur = 0;

  for (int t = 0; t < NT; ++t) {
    if (t + 1 < NT) STAGE(cur ^ 1, kt0 + (t + 1) * KVB);  // flies under compute

    // QK^T swapped: sc4[kb] = S^T[key=kb*32+rows][q=lq], keys 0..127
    f32x16 sc4[4] = {};
#pragma unroll
    for (int kb = 0; kb < 4; ++kb)
#pragma unroll
      for (int tt = 0; tt < 4; ++tt) {
        const int krow = kb * 32 + lq;
        const int cb = (tt * 32 + hi * 16) ^ ((krow & 7) << 4);
        bf16x8 kf = *(const bf16x8*)((const char*)(&sK[cur][0]) + krow * 128 + cb);
        sc4[kb] = __builtin_amdgcn_mfma_f32_32x32x16_bf16(kf, qf[tt], sc4[kb], 0, 0, 0);
      }
    // exp2 in place (scores already log2-domain)
#pragma unroll
    for (int kb = 0; kb < 4; ++kb)
#pragma unroll
      for (int r = 0; r < 16; ++r)
        sc4[kb][r] = EXP2(sc4[kb][r]);
    // pack P to bf16 pairs
    unsigned int wd[4][8];
#pragma unroll
    for (int kb = 0; kb < 4; ++kb)
#pragma unroll
      for (int g = 0; g < 8; ++g)
        wd[kb][g] = pk2(sc4[kb][2 * g], sc4[kb][2 * g + 1]);

#if HAS_K8
    // PV K=8 steps: A-frag (k = hi*4+j) = lane's OWN keys 8g+4hi+{0..3}
    union W2 { unsigned int u[2]; bf16x4 v; };
#pragma unroll
    for (int g = 0; g < 16; ++g) {
      W2 a;
      a.u[0] = wd[g >> 2][2 * (g & 3)];
      a.u[1] = wd[g >> 2][2 * (g & 3) + 1];
#pragma unroll
      for (int db = 0; db < 2; ++db) {
        const int vrow = db * 32 + lq;
        const int cb = (16 * g + 8 * hi) ^ ((vrow & 7) << 4);
        bf16x4 bv = *(const bf16x4*)((const char*)(&sV[cur][0]) + vrow * 256 + cb);
        accO[db] = __builtin_amdgcn_mfma_f32_32x32x8bf16_1k(a.v, bv, accO[db], 0, 0, 0);
      }
      accsum = __builtin_amdgcn_mfma_f32_32x32x8bf16_1k(a.v, onesv, accsum, 0, 0, 0);
    }
#else
    // fallback: packed exchange across lane^32 + 32x32x16 PV + VALU rowsum
#pragma unroll
    for (int kb = 0; kb < 4; ++kb)
#pragma unroll
      for (int r = 0; r < 16; ++r) lrun += sc4[kb][r];
    union PA { unsigned int u[4]; bf16x8 v; };
#pragma unroll
    for (int ks = 0; ks < 8; ++ks) {
      const int kb = ks >> 1;
      const int g0 = (ks & 1) * 4;
      PA pa;
      const unsigned int own0 = wd[kb][g0],     own1 = wd[kb][g0 + 1];
      const unsigned int oth0 = wd[kb][g0 + 2], oth1 = wd[kb][g0 + 3];
      const unsigned int off0 = hi ? own0 : oth0;
      const unsigned int off1 = hi ? own1 : oth1;
      const unsigned int rcv0 = (unsigned int)__shfl_xor((int)off0, 32);
      const unsigned int rcv1 = (unsigned int)__shfl_xor((int)off1, 32);
      pa.u[0] = hi ? rcv0 : own0;
      pa.u[1] = hi ? rcv1 : own1;
      pa.u[2] = hi ? oth0 : rcv0;
      pa.u[3] = hi ? oth1 : rcv1;
#pragma unroll
      for (int db = 0; db < 2; ++db) {
        const int vrow = db * 32 + lq;
        const int cb = (ks * 32 + hi * 16) ^ ((vrow & 7) << 4);
        bf16x8 vf = *(const bf16x8*)((const char*)(&sV[cur][0]) + vrow * 256 + cb);
        accO[db] = __builtin_amdgcn_mfma_f32_32x32x16_bf16(pa.v, vf, accO[db], 0, 0, 0);
      }
    }
#endif
    __syncthreads();  // next tile resident; cur reusable
    cur ^= 1;
  }
#undef STAGE

#if HAS_K8
  if (lq == 0) {
#pragma unroll
    for (int r = 0; r < 16; ++r)
      plsum[((size_t)z * NH + h) * LQS + qw0 + (r & 3) + 8 * (r >> 2) + 4 * hi] = accsum[r];
  }
#else
  lrun += __shfl_xor(lrun, 32);
  if (hi == 0)
    plsum[((size_t)z * NH + h) * LQS + qw0 + lq] = lrun;
#endif
  // O partials: C layout col=lq (d), row=(r&3)+8*(r>>2)+4*hi (q)
#pragma unroll
  for (int db = 0; db < 2; ++db)
#pragma unroll
    for (int r = 0; r < 16; ++r) {
      const int q = qw0 + (r & 3) + 8 * (r >> 2) + 4 * hi;
      pacc[(size_t)z * LQS * DMODEL + (size_t)q * DMODEL + h * HDIM + db * 32 + lq] =
          (__bf16)accO[db][r];
    }

  // ---- fused combine: last z-block for (qt,h) reduces the 4 partials ----
  __threadfence();  // release our pacc/plsum stores (L2-visible, L1 flushed)
  if (tid == 0) {
    int old = atomicAdd(&cnt[qt * NH + h], 1);
    lastf = (old == NSPLIT - 1) ? 1 : 0;
  }
  __syncthreads();
  if (lastf) {
    __threadfence();  // acquire: see all 4 z-blocks' stores
    const int qbase = qt * 128;
    for (int it = tid; it < 1024; it += 256) {
      const int row = qbase + (it >> 3);
      const int c8 = (it & 7) * 8;
      float lsum = 0.f;
#pragma unroll
      for (int zz = 0; zz < NSPLIT; ++zz)
        lsum += plsum[((size_t)zz * NH + h) * LQS + row];
      const size_t off = (size_t)row * DMODEL + h * HDIM + c8;
      float a8[8] = {};
#pragma unroll
      for (int zz = 0; zz < NSPLIT; ++zz) {
        bf16x8 v = *(const bf16x8*)(pacc + (size_t)zz * LQS * DMODEL + off);
#pragma unroll
        for (int j = 0; j < 8; ++j) a8[j] += (float)v[j];
      }
      const float inv = 1.0f / lsum;
      u16x8 o;
#pragma unroll
      for (int j = 0; j < 8; ++j) o[j] = f2bf(a8[j] * inv);
      *(u16x8*)((unsigned short*)ctx + off) = o;  // ctx aliases pacc[0]; read-then-write per thread
    }
  }
}

extern "C" void kernel_launch(void* const* d_in, const int* in_sizes, int n_in,
                              void* d_out, int out_size, void* d_ws, size_t ws_size,
                              hipStream_t stream) {
  const float* x  = (const float*)d_in[0];
  const float* hh = (const float*)d_in[1];
  const float* wq = (const float*)d_in[2];
  const float* wk = (const float*)d_in[3];
  const float* wv = (const float*)d_in[4];
  const float* wo = (const float*)d_in[5];

  unsigned short* ws = (unsigned short*)d_ws;
  const size_t E2 = (size_t)LQS * DMODEL;     // 2M elems
  const size_t E1 = (size_t)DMODEL * DMODEL;  // 1M elems
  const size_t M = 1048576;
  // Lifetime layout (u16 offsets):
  //   xb 0..2M | hb 2M..4M | wqb 4M..5M | wkb 5M..6M | wvb 6M..7M | pad 7M..8M
  //   | wob 8M..9M | Qb 9M..11M | Kb 11M..13M | Vtb 13M..15M
  //   | plsum 15M..15M+256K | cnt 15M+256K.. (+256 ints)
  // pacc (NSPLIT*2M bf16 = 8M u16) aliases [0..8M) — all dead at attn time.
  // attn's fused combine writes ctx IN-PLACE over pacc[0] (= ws+0).
  unsigned short* xb  = ws;
  unsigned short* hb  = ws + 2 * M;
  unsigned short* wqb = ws + 4 * M;
  unsigned short* wkb = ws + 5 * M;
  unsigned short* wvb = ws + 6 * M;
  unsigned short* wob = ws + 8 * M;
  unsigned short* Qb  = ws + 9 * M;
  unsigned short* Kb  = ws + 11 * M;
  unsigned short* Vtb = ws + 13 * M;
  __bf16* pacc  = (__bf16*)ws;
  float*  plsum = (float*)(ws + 15 * M);
  int*    cnt   = (int*)(ws + 15 * M + 262144);
  unsigned short* cxb = ws;  // context, in-place over pacc[0]
  const float SCL = 0.125f * 1.4426950408889634f;  // 1/sqrt(64) * log2(e)

  // one fused conversion launch (+1 block zeroing the 256 combine counters)
  CvtBatch cb;
  cb.d[0] = { x,  xb,  SCL, (unsigned)(E2 / 8) };
  cb.d[1] = { hh, hb,  1.f, (unsigned)(E2 / 8) };
  cb.d[2] = { wq, wqb, 1.f, (unsigned)(E1 / 8) };
  cb.d[3] = { wk, wkb, 1.f, (unsigned)(E1 / 8) };
  cb.d[4] = { wv, wvb, 1.f, (unsigned)(E1 / 8) };
  cb.d[5] = { wo, wob, 1.f, (unsigned)(E1 / 8) };
  cvt_all_k<<<dim3(4097), 256, 0, stream>>>(cb, cnt);

  GemmBatch3 qkv;
  qkv.d[0] = { xb, wqb, (void*)Qb,  DMODEL, 0 };
  qkv.d[1] = { hb, wkb, (void*)Kb,  DMODEL, 0 };
  qkv.d[2] = { hb, wvb, (void*)Vtb, LKS,    1 };  // V^T written directly
  gemm_bt<64, 128, false>
      <<<dim3(DMODEL / 128, LQS / 64, 3), 256, 0, stream>>>(qkv, DMODEL);

  // flat 1024-block launch; XCD-aware decode + fused combine inside (T1)
  attn_k<<<dim3(16 * NH * NSPLIT), 256, 0, stream>>>(Qb, Kb, Vtb, pacc, plsum,
                                                     cnt, (__bf16*)cxb);

  GemmBatch3 fin = {};
  fin.d[0] = { cxb, wob, d_out, DMODEL, 0 };
  gemm_bt<64, 64, true>
      <<<dim3(DMODEL / 64, LQS / 64, 1), 256, 0, stream>>>(fin, DMODEL);
}

// Round 17
// 91.331 us; speedup vs baseline: 2.4126x; 2.4126x over previous
//
#include <hip/hip_runtime.h>

typedef __bf16 bf16x8 __attribute__((ext_vector_type(8)));
typedef __bf16 bf16x4 __attribute__((ext_vector_type(4)));
typedef float f32x4 __attribute__((ext_vector_type(4)));
typedef float f32x16 __attribute__((ext_vector_type(16)));
typedef unsigned short u16x4 __attribute__((ext_vector_type(4)));
typedef unsigned short u16x8 __attribute__((ext_vector_type(8)));

#define LQS 2048
#define LKS 2048
#define DMODEL 1024
#define NH 16
#define HDIM 64
#define NSPLIT 4
#define NT 8  // KV tiles per block = (LKS/NSPLIT)/64

#if __has_builtin(__builtin_amdgcn_exp2f)
#define EXP2(x) __builtin_amdgcn_exp2f(x)
#else
#define EXP2(x) exp2f(x)
#endif

#if __has_builtin(__builtin_amdgcn_mfma_f32_32x32x8bf16_1k)
#define HAS_K8 1
#else
#define HAS_K8 0
#endif

__device__ __forceinline__ unsigned short f2bf(float f) {
  union { float f; unsigned int u; } v; v.f = f;
  unsigned int r = v.u + 0x7FFFu + ((v.u >> 16) & 1u);
  return (unsigned short)(r >> 16);
}

// pack two f32 -> one u32 of two bf16
__device__ __forceinline__ unsigned int pk2(float a, float b) {
  __bf16 lo = (__bf16)a, hi = (__bf16)b;
  unsigned short ul = __builtin_bit_cast(unsigned short, lo);
  unsigned short uh = __builtin_bit_cast(unsigned short, hi);
  return (unsigned)ul | ((unsigned)uh << 16);
}

// async global->LDS, 16B per lane; LDS dest is wave-uniform base + lane*16
#define ASYNC_CP16(gp, lp)                                                     \
  __builtin_amdgcn_global_load_lds(                                            \
      (const __attribute__((address_space(1))) unsigned int*)(gp),             \
      (__attribute__((address_space(3))) unsigned int*)(lp), 16, 0, 0)

// ---------------- fused f32 -> bf16 conversion (all 6 tensors, 1 launch) -----
struct CvtDesc { const float* src; unsigned short* dst; float scl; unsigned int nchunk; };
struct CvtBatch { CvtDesc d[6]; };

__global__ __launch_bounds__(256)
void cvt_all_k(CvtBatch cb) {
  unsigned int c = blockIdx.x * 256 + threadIdx.x;  // 8-elem chunk id
#pragma unroll
  for (int s = 0; s < 6; ++s) {
    if (c < cb.d[s].nchunk) {
      const float* src = cb.d[s].src + (size_t)c * 8;
      float4 a = *(const float4*)(src);
      float4 b = *(const float4*)(src + 4);
      const float scl = cb.d[s].scl;
      u16x8 r;
      r[0] = f2bf(a.x * scl); r[1] = f2bf(a.y * scl);
      r[2] = f2bf(a.z * scl); r[3] = f2bf(a.w * scl);
      r[4] = f2bf(b.x * scl); r[5] = f2bf(b.y * scl);
      r[6] = f2bf(b.z * scl); r[7] = f2bf(b.w * scl);
      *(u16x8*)(cb.d[s].dst + (size_t)c * 8) = r;
      return;
    }
    c -= cb.d[s].nchunk;
  }
}

// ---------------- GEMM: C[M,N] = A[M,K](bf16) * B[N,K]^T(bf16) ----------------
// Templated tile BM x BN, BK=32, 4 waves (2x2); wave owns (BM/2)x(BN/2).
// 2-phase pipeline; tiles sized for UNIFORM blocks/CU (QKV 3/CU, O-proj 2/CU).
// T2 LDS swizzle (both sides, rule #21): physical 16B-chunk p of row r holds
// global chunk p^(r&3) — staging pre-swizzles the GLOBAL source column (LDS
// dest stays linear for global_load_lds); reads XOR the chunk index.
// (Round-14 lesson: do NOT fuse per-element A work here — A is re-staged once
// per N-tile, multiplying the fused work by grid.x. Combine stays standalone.
//  Round-16 lesson: no device fences / cross-block combine inside hot kernels
//  — __threadfence = buffer_wbl2 L2-writeback, serializes the whole chip.)
struct GemmDesc { const unsigned short* A; const unsigned short* B; void* C; int ldc; int transC; };
struct GemmBatch3 { GemmDesc d[3]; };

template<int BM, int BN, bool F32OUT>
__global__ __launch_bounds__(256)
void gemm_bt(GemmBatch3 gb, int K) {
  constexpr int MFR = BM / 32;
  constexpr int NFR = BN / 32;
  const GemmDesc g = gb.d[blockIdx.z];
  __shared__ __align__(16) unsigned short sA[2][BM * 32];
  __shared__ __align__(16) unsigned short sB[2][BN * 32];
  const int tid = threadIdx.x;
  const int w = tid >> 6, l = tid & 63;
  const int wr = w >> 1, wc = w & 1;
  const int lr = l & 15, lk = (l >> 4) * 8;
  const unsigned short* Ab = g.A + (size_t)(blockIdx.y * BM) * K;
  const unsigned short* Bb = g.B + (size_t)(blockIdx.x * BN) * K;
  const int srow = w * 16 + (l >> 2);                 // staged row in 64-group
  const int scol = (((l & 3) ^ (srow & 3)) * 8);      // pre-swizzled src chunk

  auto stage = [&](int buf, int k0) {
#pragma unroll
    for (int ia = 0; ia < BM / 64; ++ia)
      ASYNC_CP16(Ab + (size_t)(ia * 64 + srow) * K + k0 + scol,
                 sA[buf] + ia * 2048 + w * 512);
#pragma unroll
    for (int ib = 0; ib < BN / 64; ++ib)
      ASYNC_CP16(Bb + (size_t)(ib * 64 + srow) * K + k0 + scol,
                 sB[buf] + ib * 2048 + w * 512);
  };

  f32x4 acc[MFR][NFR] = {};
  stage(0, 0);
  __syncthreads();
  int cur = 0;
  for (int k0 = 0; k0 < K; k0 += 32) {
    if (k0 + 32 < K) stage(cur ^ 1, k0 + 32);
    bf16x8 af[MFR], bfr[NFR];
#pragma unroll
    for (int m = 0; m < MFR; ++m) {
      const int Ar = wr * (BM / 2) + m * 16 + lr;
      af[m] = *(const bf16x8*)(sA[cur] + Ar * 32 + (((l >> 4) ^ (Ar & 3)) * 8));
    }
#pragma unroll
    for (int n = 0; n < NFR; ++n) {
      const int Br = wc * (BN / 2) + n * 16 + lr;
      bfr[n] = *(const bf16x8*)(sB[cur] + Br * 32 + (((l >> 4) ^ (Br & 3)) * 8));
    }
#pragma unroll
    for (int m = 0; m < MFR; ++m)
#pragma unroll
      for (int n = 0; n < NFR; ++n)
        acc[m][n] = __builtin_amdgcn_mfma_f32_16x16x32_bf16(af[m], bfr[n], acc[m][n], 0, 0, 0);
    __syncthreads();
    cur ^= 1;
  }
  // C/D layout: col = lane&15, row = (lane>>4)*4 + r  (m89-verified)
  const int r0 = blockIdx.y * BM + wr * (BM / 2) + (l >> 4) * 4;
  const int c0 = blockIdx.x * BN + wc * (BN / 2) + lr;
  if (g.transC) {
#pragma unroll
    for (int m = 0; m < MFR; ++m)
#pragma unroll
      for (int n = 0; n < NFR; ++n) {
        u16x4 v;
#pragma unroll
        for (int r = 0; r < 4; ++r) v[r] = f2bf(acc[m][n][r]);
        *(u16x4*)((unsigned short*)g.C + (size_t)(c0 + n * 16) * g.ldc + r0 + m * 16) = v;
      }
  } else {
#pragma unroll
    for (int m = 0; m < MFR; ++m)
#pragma unroll
      for (int n = 0; n < NFR; ++n)
#pragma unroll
        for (int r = 0; r < 4; ++r) {
          size_t idx = (size_t)(r0 + m * 16 + r) * g.ldc + c0 + n * 16;
          if (F32OUT) ((float*)g.C)[idx] = acc[m][n][r];
          else        ((unsigned short*)g.C)[idx] = f2bf(acc[m][n][r]);
        }
  }
}

// ---------------- flash attention, fixed-max (exact; log2-domain scores) -----
// 32x32x16 swapped QK^T; P in registers; PV + rowsum via mfma_32x32x8bf16_1k.
// T1 XCD-aware block decode; 3 LDS buffers, 2 tiles ahead, counted vmcnt.
__global__ __launch_bounds__(256)
void attn_k(const unsigned short* __restrict__ Q, const unsigned short* __restrict__ K,
            const unsigned short* __restrict__ Vt,
            __bf16* __restrict__ pacc, float* __restrict__ plsum) {
  __shared__ __align__(16) __bf16 sK[3][64 * 64];  // 8KB per buf
  __shared__ __align__(16) __bf16 sV[3][64 * 64];
  // T1 decode: combo c (= h + 16z) pinned to XCD c%8
  const int b = blockIdx.x;
  const int xcd = b & 7, rr = b >> 3;
  const int qt = rr & 15, chi = rr >> 4;
  const int c = xcd + 8 * chi;
  const int h = c & 15, z = c >> 4;
  const int tid = threadIdx.x;
  const int w = tid >> 6, l = tid & 63;
  const int lq = l & 31;   // q-column lane (C col = lane&31)
  const int hi = l >> 5;   // k-half selector
  const int qw0 = qt * 128 + w * 32;

  const int srow = l >> 3;
  const int scolb = (l & 7) * 16;

  // Q as B-frag: qf[t] = Q[qw0+lq][h*64 + t*16 + hi*8 .. +7]
  bf16x8 qf[4];
#pragma unroll
  for (int t = 0; t < 4; ++t)
    qf[t] = *(const bf16x8*)(Q + (size_t)(qw0 + lq) * DMODEL + h * HDIM + t * 16 + hi * 8);

  f32x16 accO[2] = {};   // O[q rows via C-layout][d = db*32 + lq]
#if HAS_K8
  f32x16 accsum = {};    // rowsum via ones-B MFMA
  bf16x4 onesv;
#pragma unroll
  for (int j = 0; j < 4; ++j) onesv[j] = (__bf16)1.0f;
#else
  float lrun = 0.f;
#endif

  const int kt0 = z * (LKS / NSPLIT);

#define STAGE(B, KT)                                                           \
  do {                                                                         \
    _Pragma("unroll")                                                          \
    for (int i_ = 0; i_ < 2; ++i_) {                                           \
      const int row_ = (w * 2 + i_) * 8 + srow;                                \
      const int sc_ = scolb ^ ((row_ & 7) << 4);                               \
      ASYNC_CP16(K + (size_t)((KT) + row_) * DMODEL + h * HDIM + sc_ / 2,      \
                 (char*)(&sK[B][0]) + (w * 2 + i_) * 1024);                    \
      ASYNC_CP16(Vt + (size_t)(h * HDIM + row_) * LKS + (KT) + sc_ / 2,        \
                 (char*)(&sV[B][0]) + (w * 2 + i_) * 1024);                    \
    }                                                                          \
  } while (0)

  STAGE(0, kt0);
  STAGE(1, kt0 + 64);

#pragma unroll
  for (int t = 0; t < NT; ++t) {
    if (t >= 1) {
      __builtin_amdgcn_sched_barrier(0);
      __builtin_amdgcn_s_barrier();  // buf[(t+2)%3] readers (tile t-1) done
    }
    if (t + 2 < NT) STAGE((t + 2) % 3, kt0 + (t + 2) * 64);
    if (t < NT - 2)       asm volatile("s_waitcnt vmcnt(8)" ::: "memory");
    else if (t == NT - 2) asm volatile("s_waitcnt vmcnt(4)" ::: "memory");
    else                  asm volatile("s_waitcnt vmcnt(0)" ::: "memory");
    __builtin_amdgcn_s_barrier();    // tile t resident for ALL waves
    __builtin_amdgcn_sched_barrier(0);
    const int cur = t % 3;

    // QK^T swapped: sc[kb] = S^T[key=kb*32+rows][q=lq]
    f32x16 sc[2] = {};
#pragma unroll
    for (int kb = 0; kb < 2; ++kb)
#pragma unroll
      for (int tt = 0; tt < 4; ++tt) {
        const int krow = kb * 32 + lq;
        const int cb = (tt * 32 + hi * 16) ^ ((krow & 7) << 4);
        bf16x8 kf = *(const bf16x8*)((const char*)(&sK[cur][0]) + krow * 128 + cb);
        sc[kb] = __builtin_amdgcn_mfma_f32_32x32x16_bf16(kf, qf[tt], sc[kb], 0, 0, 0);
      }
    // exp2 in place (scores already log2-domain)
#pragma unroll
    for (int kb = 0; kb < 2; ++kb)
#pragma unroll
      for (int r = 0; r < 16; ++r)
        sc[kb][r] = EXP2(sc[kb][r]);
    // pack P to bf16 pairs: wd[kb][g] = {sc[2g], sc[2g+1]}
    unsigned int wd[2][8];
#pragma unroll
    for (int kb = 0; kb < 2; ++kb)
#pragma unroll
      for (int g = 0; g < 8; ++g)
        wd[kb][g] = pk2(sc[kb][2 * g], sc[kb][2 * g + 1]);

#if HAS_K8
    // PV with K=8 steps: A-frag (k = hi*4 + j) = lane's OWN keys 8g+4hi+{0..3}
    union W2 { unsigned int u[2]; bf16x4 v; };
#pragma unroll
    for (int g = 0; g < 8; ++g) {
      W2 a;
      a.u[0] = wd[g >> 2][2 * (g & 3)];
      a.u[1] = wd[g >> 2][2 * (g & 3) + 1];
#pragma unroll
      for (int db = 0; db < 2; ++db) {
        const int vrow = db * 32 + lq;
        const int cb = (16 * g + 8 * hi) ^ ((vrow & 7) << 4);
        bf16x4 bv = *(const bf16x4*)((const char*)(&sV[cur][0]) + vrow * 128 + cb);
        accO[db] = __builtin_amdgcn_mfma_f32_32x32x8bf16_1k(a.v, bv, accO[db], 0, 0, 0);
      }
      // rowsum on the matrix pipe: B = ones
      accsum = __builtin_amdgcn_mfma_f32_32x32x8bf16_1k(a.v, onesv, accsum, 0, 0, 0);
    }
#else
    // fallback: packed exchange across lane^32 + 32x32x16 PV + VALU rowsum
#pragma unroll
    for (int kb = 0; kb < 2; ++kb)
#pragma unroll
      for (int r = 0; r < 16; ++r) lrun += sc[kb][r];
    union PA { unsigned int u[4]; bf16x8 v; };
    PA pa[4];
#pragma unroll
    for (int ks = 0; ks < 4; ++ks) {
      const int kb = ks >> 1;
      const int g0 = (ks & 1) * 4;
      const unsigned int own0 = wd[kb][g0],     own1 = wd[kb][g0 + 1];
      const unsigned int oth0 = wd[kb][g0 + 2], oth1 = wd[kb][g0 + 3];
      const unsigned int off0 = hi ? own0 : oth0;
      const unsigned int off1 = hi ? own1 : oth1;
      const unsigned int rcv0 = (unsigned int)__shfl_xor((int)off0, 32);
      const unsigned int rcv1 = (unsigned int)__shfl_xor((int)off1, 32);
      pa[ks].u[0] = hi ? rcv0 : own0;
      pa[ks].u[1] = hi ? rcv1 : own1;
      pa[ks].u[2] = hi ? oth0 : rcv0;
      pa[ks].u[3] = hi ? oth1 : rcv1;
    }
#pragma unroll
    for (int db = 0; db < 2; ++db)
#pragma unroll
      for (int ks = 0; ks < 4; ++ks) {
        const int vrow = db * 32 + lq;
        const int cb = (ks * 32 + hi * 16) ^ ((vrow & 7) << 4);
        bf16x8 vf = *(const bf16x8*)((const char*)(&sV[cur][0]) + vrow * 128 + cb);
        accO[db] = __builtin_amdgcn_mfma_f32_32x32x16_bf16(pa[ks].v, vf, accO[db], 0, 0, 0);
      }
#endif
  }
#undef STAGE

#if HAS_K8
  if (lq == 0) {
#pragma unroll
    for (int r = 0; r < 16; ++r)
      plsum[((size_t)z * NH + h) * LQS + qw0 + (r & 3) + 8 * (r >> 2) + 4 * hi] = accsum[r];
  }
#else
  lrun += __shfl_xor(lrun, 32);
  if (hi == 0)
    plsum[((size_t)z * NH + h) * LQS + qw0 + lq] = lrun;
#endif
  // O partials: C layout col=lq (d), row=(r&3)+8*(r>>2)+4*hi (q)
#pragma unroll
  for (int db = 0; db < 2; ++db)
#pragma unroll
    for (int r = 0; r < 16; ++r) {
      const int q = qw0 + (r & 3) + 8 * (r >> 2) + 4 * hi;
      pacc[(size_t)z * LQS * DMODEL + (size_t)q * DMODEL + h * HDIM + db * 32 + lq] =
          (__bf16)accO[db][r];
    }
}

// ---------------- combine: ctx = (sum_z pacc_z) / (sum_z lsum_z) --------------
// NOTE: ctx aliases pacc[0] (in-place per-thread: read all z, then write same
// addresses) — no __restrict__ on pacc/ctx so the compiler keeps the order.
__global__ __launch_bounds__(256)
void combine_k(const __bf16* pacc, const float* __restrict__ plsum, __bf16* ctx) {
  const size_t e = ((size_t)blockIdx.x * 256 + threadIdx.x) * 8;
  const int row = (int)(e >> 10), d0 = (int)(e & 1023), h = d0 >> 6;
  float lsum = 0.f;
  float acc[8] = {};
#pragma unroll
  for (int z = 0; z < NSPLIT; ++z) {
    lsum += plsum[((size_t)z * NH + h) * LQS + row];
    bf16x8 v = *(const bf16x8*)(pacc + (size_t)z * LQS * DMODEL + e);
#pragma unroll
    for (int j = 0; j < 8; ++j) acc[j] += (float)v[j];
  }
  float inv = 1.0f / lsum;
  bf16x8 r;
#pragma unroll
  for (int j = 0; j < 8; ++j) r[j] = (__bf16)(acc[j] * inv);
  *(bf16x8*)(ctx + e) = r;
}

extern "C" void kernel_launch(void* const* d_in, const int* in_sizes, int n_in,
                              void* d_out, int out_size, void* d_ws, size_t ws_size,
                              hipStream_t stream) {
  const float* x  = (const float*)d_in[0];
  const float* hh = (const float*)d_in[1];
  const float* wq = (const float*)d_in[2];
  const float* wk = (const float*)d_in[3];
  const float* wv = (const float*)d_in[4];
  const float* wo = (const float*)d_in[5];

  unsigned short* ws = (unsigned short*)d_ws;
  const size_t E2 = (size_t)LQS * DMODEL;     // 2M elems
  const size_t E1 = (size_t)DMODEL * DMODEL;  // 1M elems
  const size_t M = 1048576;
  // Lifetime layout (u16 offsets):
  //   xb 0..2M | hb 2M..4M | wqb 4M..5M | wkb 5M..6M | wvb 6M..7M | pad 7M..8M
  //   | wob 8M..9M | Qb 9M..11M | Kb 11M..13M | Vtb 13M..15M | plsum 15M..16M
  // pacc (NSPLIT*2M bf16 = 8M u16) aliases [0..8M) — all dead at attn time.
  // combine writes ctx IN-PLACE over pacc[0] (= ws+0); final GEMM reads it.
  unsigned short* xb  = ws;
  unsigned short* hb  = ws + 2 * M;
  unsigned short* wqb = ws + 4 * M;
  unsigned short* wkb = ws + 5 * M;
  unsigned short* wvb = ws + 6 * M;
  unsigned short* wob = ws + 8 * M;
  unsigned short* Qb  = ws + 9 * M;
  unsigned short* Kb  = ws + 11 * M;
  unsigned short* Vtb = ws + 13 * M;
  __bf16* pacc  = (__bf16*)ws;
  float*  plsum = (float*)(ws + 15 * M);
  unsigned short* cxb = ws;  // context, in-place over pacc[0]
  const float SCL = 0.125f * 1.4426950408889634f;  // 1/sqrt(64) * log2(e)

  // one fused conversion launch: 2M+2M+1M*4 = 8M elems = 1M 8-elem chunks
  CvtBatch cb;
  cb.d[0] = { x,  xb,  SCL, (unsigned)(E2 / 8) };
  cb.d[1] = { hh, hb,  1.f, (unsigned)(E2 / 8) };
  cb.d[2] = { wq, wqb, 1.f, (unsigned)(E1 / 8) };
  cb.d[3] = { wk, wkb, 1.f, (unsigned)(E1 / 8) };
  cb.d[4] = { wv, wvb, 1.f, (unsigned)(E1 / 8) };
  cb.d[5] = { wo, wob, 1.f, (unsigned)(E1 / 8) };
  cvt_all_k<<<dim3(4096), 256, 0, stream>>>(cb);

  GemmBatch3 qkv;
  qkv.d[0] = { xb, wqb, (void*)Qb,  DMODEL, 0 };
  qkv.d[1] = { hb, wkb, (void*)Kb,  DMODEL, 0 };
  qkv.d[2] = { hb, wvb, (void*)Vtb, LKS,    1 };  // V^T written directly
  gemm_bt<64, 128, false>
      <<<dim3(DMODEL / 128, LQS / 64, 3), 256, 0, stream>>>(qkv, DMODEL);

  // flat 1024-block launch; XCD-aware decode inside the kernel (T1)
  attn_k<<<dim3(16 * NH * NSPLIT), 256, 0, stream>>>(Qb, Kb, Vtb, pacc, plsum);

  combine_k<<<dim3((unsigned)(E2 / 2048)), 256, 0, stream>>>(pacc, plsum, (__bf16*)cxb);

  GemmBatch3 fin = {};
  fin.d[0] = { cxb, wob, d_out, DMODEL, 0 };
  gemm_bt<64, 64, true>
      <<<dim3(DMODEL / 64, LQS / 64, 1), 256, 0, stream>>>(fin, DMODEL);
}

// Round 18
// 84.616 us; speedup vs baseline: 2.6040x; 1.0794x over previous
//
#include <hip/hip_runtime.h>

typedef __bf16 bf16x8 __attribute__((ext_vector_type(8)));
typedef __bf16 bf16x4 __attribute__((ext_vector_type(4)));
typedef float f32x4 __attribute__((ext_vector_type(4)));
typedef float f32x16 __attribute__((ext_vector_type(16)));
typedef unsigned short u16x4 __attribute__((ext_vector_type(4)));
typedef unsigned short u16x8 __attribute__((ext_vector_type(8)));

#define LQS 2048
#define LKS 2048
#define DMODEL 1024
#define NH 16
#define HDIM 64
#define NSPLIT 2
#define NT 16  // KV tiles per block = (LKS/NSPLIT)/64

#if __has_builtin(__builtin_amdgcn_exp2f)
#define EXP2(x) __builtin_amdgcn_exp2f(x)
#else
#define EXP2(x) exp2f(x)
#endif

#if __has_builtin(__builtin_amdgcn_mfma_f32_32x32x8bf16_1k)
#define HAS_K8 1
#else
#define HAS_K8 0
#endif

__device__ __forceinline__ unsigned short f2bf(float f) {
  union { float f; unsigned int u; } v; v.f = f;
  unsigned int r = v.u + 0x7FFFu + ((v.u >> 16) & 1u);
  return (unsigned short)(r >> 16);
}

// pack two f32 -> one u32 of two bf16
__device__ __forceinline__ unsigned int pk2(float a, float b) {
  __bf16 lo = (__bf16)a, hi = (__bf16)b;
  unsigned short ul = __builtin_bit_cast(unsigned short, lo);
  unsigned short uh = __builtin_bit_cast(unsigned short, hi);
  return (unsigned)ul | ((unsigned)uh << 16);
}

// async global->LDS, 16B per lane; LDS dest is wave-uniform base + lane*16
#define ASYNC_CP16(gp, lp)                                                     \
  __builtin_amdgcn_global_load_lds(                                            \
      (const __attribute__((address_space(1))) unsigned int*)(gp),             \
      (__attribute__((address_space(3))) unsigned int*)(lp), 16, 0, 0)

// ---------------- fused f32 -> bf16 conversion (all 6 tensors, 1 launch) -----
struct CvtDesc { const float* src; unsigned short* dst; float scl; unsigned int nchunk; };
struct CvtBatch { CvtDesc d[6]; };

__global__ __launch_bounds__(256)
void cvt_all_k(CvtBatch cb) {
  unsigned int c = blockIdx.x * 256 + threadIdx.x;  // 8-elem chunk id
#pragma unroll
  for (int s = 0; s < 6; ++s) {
    if (c < cb.d[s].nchunk) {
      const float* src = cb.d[s].src + (size_t)c * 8;
      float4 a = *(const float4*)(src);
      float4 b = *(const float4*)(src + 4);
      const float scl = cb.d[s].scl;
      u16x8 r;
      r[0] = f2bf(a.x * scl); r[1] = f2bf(a.y * scl);
      r[2] = f2bf(a.z * scl); r[3] = f2bf(a.w * scl);
      r[4] = f2bf(b.x * scl); r[5] = f2bf(b.y * scl);
      r[6] = f2bf(b.z * scl); r[7] = f2bf(b.w * scl);
      *(u16x8*)(cb.d[s].dst + (size_t)c * 8) = r;
      return;
    }
    c -= cb.d[s].nchunk;
  }
}

// ---------------- GEMM: C[M,N] = A[M,K](bf16) * B[N,K]^T(bf16) ----------------
// Templated tile BM x BN, BK=64 via TWO 32-wide panels per buffer (identical
// staging/swizzle per panel as the proven BK=32 code) -> HALF the barriers.
// 2-phase pipeline; tiles sized for UNIFORM blocks/CU (QKV 3/CU, O-proj 2/CU).
// T2 LDS swizzle (both sides, rule #21): physical 16B-chunk p of row r holds
// global chunk p^(r&3) — staging pre-swizzles the GLOBAL source column (LDS
// dest stays linear for global_load_lds); reads XOR the chunk index.
// (Round-14 lesson: do NOT fuse per-element A work here — A is re-staged once
// per N-tile, multiplying the fused work by grid.x. Combine stays standalone.
//  Round-16 lesson: no device fences / cross-block combine inside hot kernels
//  — __threadfence = buffer_wbl2 L2-writeback, serializes the whole chip.)
struct GemmDesc { const unsigned short* A; const unsigned short* B; void* C; int ldc; int transC; };
struct GemmBatch3 { GemmDesc d[3]; };

template<int BM, int BN, bool F32OUT>
__global__ __launch_bounds__(256)
void gemm_bt(GemmBatch3 gb, int K) {
  constexpr int MFR = BM / 32;
  constexpr int NFR = BN / 32;
  const GemmDesc g = gb.d[blockIdx.z];
  __shared__ __align__(16) unsigned short sA[2][2][BM * 32];  // [buf][panel]
  __shared__ __align__(16) unsigned short sB[2][2][BN * 32];
  const int tid = threadIdx.x;
  const int w = tid >> 6, l = tid & 63;
  const int wr = w >> 1, wc = w & 1;
  const int lr = l & 15, lk = (l >> 4) * 8;
  const unsigned short* Ab = g.A + (size_t)(blockIdx.y * BM) * K;
  const unsigned short* Bb = g.B + (size_t)(blockIdx.x * BN) * K;
  const int srow = w * 16 + (l >> 2);                 // staged row in 64-group
  const int scol = (((l & 3) ^ (srow & 3)) * 8);      // pre-swizzled src chunk

  auto stage = [&](int buf, int k0) {
#pragma unroll
    for (int p = 0; p < 2; ++p) {
#pragma unroll
      for (int ia = 0; ia < BM / 64; ++ia)
        ASYNC_CP16(Ab + (size_t)(ia * 64 + srow) * K + k0 + p * 32 + scol,
                   sA[buf][p] + ia * 2048 + w * 512);
#pragma unroll
      for (int ib = 0; ib < BN / 64; ++ib)
        ASYNC_CP16(Bb + (size_t)(ib * 64 + srow) * K + k0 + p * 32 + scol,
                   sB[buf][p] + ib * 2048 + w * 512);
    }
  };

  f32x4 acc[MFR][NFR] = {};
  stage(0, 0);
  __syncthreads();
  int cur = 0;
  for (int k0 = 0; k0 < K; k0 += 64) {
    if (k0 + 64 < K) stage(cur ^ 1, k0 + 64);
#pragma unroll
    for (int p = 0; p < 2; ++p) {
      bf16x8 af[MFR], bfr[NFR];
#pragma unroll
      for (int m = 0; m < MFR; ++m) {
        const int Ar = wr * (BM / 2) + m * 16 + lr;
        af[m] = *(const bf16x8*)(sA[cur][p] + Ar * 32 + (((l >> 4) ^ (Ar & 3)) * 8));
      }
#pragma unroll
      for (int n = 0; n < NFR; ++n) {
        const int Br = wc * (BN / 2) + n * 16 + lr;
        bfr[n] = *(const bf16x8*)(sB[cur][p] + Br * 32 + (((l >> 4) ^ (Br & 3)) * 8));
      }
#pragma unroll
      for (int m = 0; m < MFR; ++m)
#pragma unroll
        for (int n = 0; n < NFR; ++n)
          acc[m][n] = __builtin_amdgcn_mfma_f32_16x16x32_bf16(af[m], bfr[n], acc[m][n], 0, 0, 0);
    }
    __syncthreads();
    cur ^= 1;
  }
  // C/D layout: col = lane&15, row = (lane>>4)*4 + r  (m89-verified)
  const int r0 = blockIdx.y * BM + wr * (BM / 2) + (l >> 4) * 4;
  const int c0 = blockIdx.x * BN + wc * (BN / 2) + lr;
  if (g.transC) {
#pragma unroll
    for (int m = 0; m < MFR; ++m)
#pragma unroll
      for (int n = 0; n < NFR; ++n) {
        u16x4 v;
#pragma unroll
        for (int r = 0; r < 4; ++r) v[r] = f2bf(acc[m][n][r]);
        *(u16x4*)((unsigned short*)g.C + (size_t)(c0 + n * 16) * g.ldc + r0 + m * 16) = v;
      }
  } else {
#pragma unroll
    for (int m = 0; m < MFR; ++m)
#pragma unroll
      for (int n = 0; n < NFR; ++n)
#pragma unroll
        for (int r = 0; r < 4; ++r) {
          size_t idx = (size_t)(r0 + m * 16 + r) * g.ldc + c0 + n * 16;
          if (F32OUT) ((float*)g.C)[idx] = acc[m][n][r];
          else        ((unsigned short*)g.C)[idx] = f2bf(acc[m][n][r]);
        }
  }
}

// ---------------- flash attention, fixed-max (exact; log2-domain scores) -----
// 32x32x16 swapped QK^T; P in registers; PV + rowsum via mfma_32x32x8bf16_1k.
// T1 XCD-aware block decode; 3 LDS buffers, 2 tiles ahead, counted vmcnt.
// NSPLIT=2: halves pacc/plsum partial traffic + combine work (occupancy was
// measured non-binding in R8/R9).
__global__ __launch_bounds__(256)
void attn_k(const unsigned short* __restrict__ Q, const unsigned short* __restrict__ K,
            const unsigned short* __restrict__ Vt,
            __bf16* __restrict__ pacc, float* __restrict__ plsum) {
  __shared__ __align__(16) __bf16 sK[3][64 * 64];  // 8KB per buf
  __shared__ __align__(16) __bf16 sV[3][64 * 64];
  // T1 decode: combo c (= h + 16z) pinned to XCD c%8
  const int b = blockIdx.x;
  const int xcd = b & 7, rr = b >> 3;
  const int qt = rr & 15, chi = rr >> 4;
  const int c = xcd + 8 * chi;
  const int h = c & 15, z = c >> 4;
  const int tid = threadIdx.x;
  const int w = tid >> 6, l = tid & 63;
  const int lq = l & 31;   // q-column lane (C col = lane&31)
  const int hi = l >> 5;   // k-half selector
  const int qw0 = qt * 128 + w * 32;

  const int srow = l >> 3;
  const int scolb = (l & 7) * 16;

  // Q as B-frag: qf[t] = Q[qw0+lq][h*64 + t*16 + hi*8 .. +7]
  bf16x8 qf[4];
#pragma unroll
  for (int t = 0; t < 4; ++t)
    qf[t] = *(const bf16x8*)(Q + (size_t)(qw0 + lq) * DMODEL + h * HDIM + t * 16 + hi * 8);

  f32x16 accO[2] = {};   // O[q rows via C-layout][d = db*32 + lq]
#if HAS_K8
  f32x16 accsum = {};    // rowsum via ones-B MFMA
  bf16x4 onesv;
#pragma unroll
  for (int j = 0; j < 4; ++j) onesv[j] = (__bf16)1.0f;
#else
  float lrun = 0.f;
#endif

  const int kt0 = z * (LKS / NSPLIT);

#define STAGE(B, KT)                                                           \
  do {                                                                         \
    _Pragma("unroll")                                                          \
    for (int i_ = 0; i_ < 2; ++i_) {                                           \
      const int row_ = (w * 2 + i_) * 8 + srow;                                \
      const int sc_ = scolb ^ ((row_ & 7) << 4);                               \
      ASYNC_CP16(K + (size_t)((KT) + row_) * DMODEL + h * HDIM + sc_ / 2,      \
                 (char*)(&sK[B][0]) + (w * 2 + i_) * 1024);                    \
      ASYNC_CP16(Vt + (size_t)(h * HDIM + row_) * LKS + (KT) + sc_ / 2,        \
                 (char*)(&sV[B][0]) + (w * 2 + i_) * 1024);                    \
    }                                                                          \
  } while (0)

  STAGE(0, kt0);
  STAGE(1, kt0 + 64);

#pragma unroll
  for (int t = 0; t < NT; ++t) {
    if (t >= 1) {
      __builtin_amdgcn_sched_barrier(0);
      __builtin_amdgcn_s_barrier();  // buf[(t+2)%3] readers (tile t-1) done
    }
    if (t + 2 < NT) STAGE((t + 2) % 3, kt0 + (t + 2) * 64);
    if (t < NT - 2)       asm volatile("s_waitcnt vmcnt(8)" ::: "memory");
    else if (t == NT - 2) asm volatile("s_waitcnt vmcnt(4)" ::: "memory");
    else                  asm volatile("s_waitcnt vmcnt(0)" ::: "memory");
    __builtin_amdgcn_s_barrier();    // tile t resident for ALL waves
    __builtin_amdgcn_sched_barrier(0);
    const int cur = t % 3;

    // QK^T swapped: sc[kb] = S^T[key=kb*32+rows][q=lq]
    f32x16 sc[2] = {};
#pragma unroll
    for (int kb = 0; kb < 2; ++kb)
#pragma unroll
      for (int tt = 0; tt < 4; ++tt) {
        const int krow = kb * 32 + lq;
        const int cb = (tt * 32 + hi * 16) ^ ((krow & 7) << 4);
        bf16x8 kf = *(const bf16x8*)((const char*)(&sK[cur][0]) + krow * 128 + cb);
        sc[kb] = __builtin_amdgcn_mfma_f32_32x32x16_bf16(kf, qf[tt], sc[kb], 0, 0, 0);
      }
    // exp2 in place (scores already log2-domain)
#pragma unroll
    for (int kb = 0; kb < 2; ++kb)
#pragma unroll
      for (int r = 0; r < 16; ++r)
        sc[kb][r] = EXP2(sc[kb][r]);
    // pack P to bf16 pairs: wd[kb][g] = {sc[2g], sc[2g+1]}
    unsigned int wd[2][8];
#pragma unroll
    for (int kb = 0; kb < 2; ++kb)
#pragma unroll
      for (int g = 0; g < 8; ++g)
        wd[kb][g] = pk2(sc[kb][2 * g], sc[kb][2 * g + 1]);

#if HAS_K8
    // PV with K=8 steps: A-frag (k = hi*4 + j) = lane's OWN keys 8g+4hi+{0..3}
    union W2 { unsigned int u[2]; bf16x4 v; };
#pragma unroll
    for (int g = 0; g < 8; ++g) {
      W2 a;
      a.u[0] = wd[g >> 2][2 * (g & 3)];
      a.u[1] = wd[g >> 2][2 * (g & 3) + 1];
#pragma unroll
      for (int db = 0; db < 2; ++db) {
        const int vrow = db * 32 + lq;
        const int cb = (16 * g + 8 * hi) ^ ((vrow & 7) << 4);
        bf16x4 bv = *(const bf16x4*)((const char*)(&sV[cur][0]) + vrow * 128 + cb);
        accO[db] = __builtin_amdgcn_mfma_f32_32x32x8bf16_1k(a.v, bv, accO[db], 0, 0, 0);
      }
      // rowsum on the matrix pipe: B = ones
      accsum = __builtin_amdgcn_mfma_f32_32x32x8bf16_1k(a.v, onesv, accsum, 0, 0, 0);
    }
#else
    // fallback: packed exchange across lane^32 + 32x32x16 PV + VALU rowsum
#pragma unroll
    for (int kb = 0; kb < 2; ++kb)
#pragma unroll
      for (int r = 0; r < 16; ++r) lrun += sc[kb][r];
    union PA { unsigned int u[4]; bf16x8 v; };
    PA pa[4];
#pragma unroll
    for (int ks = 0; ks < 4; ++ks) {
      const int kb = ks >> 1;
      const int g0 = (ks & 1) * 4;
      const unsigned int own0 = wd[kb][g0],     own1 = wd[kb][g0 + 1];
      const unsigned int oth0 = wd[kb][g0 + 2], oth1 = wd[kb][g0 + 3];
      const unsigned int off0 = hi ? own0 : oth0;
      const unsigned int off1 = hi ? own1 : oth1;
      const unsigned int rcv0 = (unsigned int)__shfl_xor((int)off0, 32);
      const unsigned int rcv1 = (unsigned int)__shfl_xor((int)off1, 32);
      pa[ks].u[0] = hi ? rcv0 : own0;
      pa[ks].u[1] = hi ? rcv1 : own1;
      pa[ks].u[2] = hi ? oth0 : rcv0;
      pa[ks].u[3] = hi ? oth1 : rcv1;
    }
#pragma unroll
    for (int db = 0; db < 2; ++db)
#pragma unroll
      for (int ks = 0; ks < 4; ++ks) {
        const int vrow = db * 32 + lq;
        const int cb = (ks * 32 + hi * 16) ^ ((vrow & 7) << 4);
        bf16x8 vf = *(const bf16x8*)((const char*)(&sV[cur][0]) + vrow * 128 + cb);
        accO[db] = __builtin_amdgcn_mfma_f32_32x32x16_bf16(pa[ks].v, vf, accO[db], 0, 0, 0);
      }
#endif
  }
#undef STAGE

#if HAS_K8
  if (lq == 0) {
#pragma unroll
    for (int r = 0; r < 16; ++r)
      plsum[((size_t)z * NH + h) * LQS + qw0 + (r & 3) + 8 * (r >> 2) + 4 * hi] = accsum[r];
  }
#else
  lrun += __shfl_xor(lrun, 32);
  if (hi == 0)
    plsum[((size_t)z * NH + h) * LQS + qw0 + lq] = lrun;
#endif
  // O partials: C layout col=lq (d), row=(r&3)+8*(r>>2)+4*hi (q)
#pragma unroll
  for (int db = 0; db < 2; ++db)
#pragma unroll
    for (int r = 0; r < 16; ++r) {
      const int q = qw0 + (r & 3) + 8 * (r >> 2) + 4 * hi;
      pacc[(size_t)z * LQS * DMODEL + (size_t)q * DMODEL + h * HDIM + db * 32 + lq] =
          (__bf16)accO[db][r];
    }
}

// ---------------- combine: ctx = (sum_z pacc_z) / (sum_z lsum_z) --------------
// NOTE: ctx aliases pacc[0] (in-place per-thread: read all z, then write same
// addresses) — no __restrict__ on pacc/ctx so the compiler keeps the order.
__global__ __launch_bounds__(256)
void combine_k(const __bf16* pacc, const float* __restrict__ plsum, __bf16* ctx) {
  const size_t e = ((size_t)blockIdx.x * 256 + threadIdx.x) * 8;
  const int row = (int)(e >> 10), d0 = (int)(e & 1023), h = d0 >> 6;
  float lsum = 0.f;
  float acc[8] = {};
#pragma unroll
  for (int z = 0; z < NSPLIT; ++z) {
    lsum += plsum[((size_t)z * NH + h) * LQS + row];
    bf16x8 v = *(const bf16x8*)(pacc + (size_t)z * LQS * DMODEL + e);
#pragma unroll
    for (int j = 0; j < 8; ++j) acc[j] += (float)v[j];
  }
  float inv = 1.0f / lsum;
  bf16x8 r;
#pragma unroll
  for (int j = 0; j < 8; ++j) r[j] = (__bf16)(acc[j] * inv);
  *(bf16x8*)(ctx + e) = r;
}

extern "C" void kernel_launch(void* const* d_in, const int* in_sizes, int n_in,
                              void* d_out, int out_size, void* d_ws, size_t ws_size,
                              hipStream_t stream) {
  const float* x  = (const float*)d_in[0];
  const float* hh = (const float*)d_in[1];
  const float* wq = (const float*)d_in[2];
  const float* wk = (const float*)d_in[3];
  const float* wv = (const float*)d_in[4];
  const float* wo = (const float*)d_in[5];

  unsigned short* ws = (unsigned short*)d_ws;
  const size_t E2 = (size_t)LQS * DMODEL;     // 2M elems
  const size_t E1 = (size_t)DMODEL * DMODEL;  // 1M elems
  const size_t M = 1048576;
  // Lifetime layout (u16 offsets):
  //   xb 0..2M | hb 2M..4M | wqb 4M..5M | wkb 5M..6M | wvb 6M..7M | pad 7M..8M
  //   | wob 8M..9M | Qb 9M..11M | Kb 11M..13M | Vtb 13M..15M | plsum 15M..16M
  // pacc (NSPLIT=2 x 2M bf16 = 4M u16) aliases [0..4M) — dead at attn time.
  // combine writes ctx IN-PLACE over pacc[0] (= ws+0); final GEMM reads it.
  unsigned short* xb  = ws;
  unsigned short* hb  = ws + 2 * M;
  unsigned short* wqb = ws + 4 * M;
  unsigned short* wkb = ws + 5 * M;
  unsigned short* wvb = ws + 6 * M;
  unsigned short* wob = ws + 8 * M;
  unsigned short* Qb  = ws + 9 * M;
  unsigned short* Kb  = ws + 11 * M;
  unsigned short* Vtb = ws + 13 * M;
  __bf16* pacc  = (__bf16*)ws;
  float*  plsum = (float*)(ws + 15 * M);
  unsigned short* cxb = ws;  // context, in-place over pacc[0]
  const float SCL = 0.125f * 1.4426950408889634f;  // 1/sqrt(64) * log2(e)

  // one fused conversion launch: 2M+2M+1M*4 = 8M elems = 1M 8-elem chunks
  CvtBatch cb;
  cb.d[0] = { x,  xb,  SCL, (unsigned)(E2 / 8) };
  cb.d[1] = { hh, hb,  1.f, (unsigned)(E2 / 8) };
  cb.d[2] = { wq, wqb, 1.f, (unsigned)(E1 / 8) };
  cb.d[3] = { wk, wkb, 1.f, (unsigned)(E1 / 8) };
  cb.d[4] = { wv, wvb, 1.f, (unsigned)(E1 / 8) };
  cb.d[5] = { wo, wob, 1.f, (unsigned)(E1 / 8) };
  cvt_all_k<<<dim3(4096), 256, 0, stream>>>(cb);

  GemmBatch3 qkv;
  qkv.d[0] = { xb, wqb, (void*)Qb,  DMODEL, 0 };
  qkv.d[1] = { hb, wkb, (void*)Kb,  DMODEL, 0 };
  qkv.d[2] = { hb, wvb, (void*)Vtb, LKS,    1 };  // V^T written directly
  gemm_bt<64, 128, false>
      <<<dim3(DMODEL / 128, LQS / 64, 3), 256, 0, stream>>>(qkv, DMODEL);

  // flat 512-block launch; XCD-aware decode inside the kernel (T1)
  attn_k<<<dim3(16 * NH * NSPLIT), 256, 0, stream>>>(Qb, Kb, Vtb, pacc, plsum);

  combine_k<<<dim3((unsigned)(E2 / 2048)), 256, 0, stream>>>(pacc, plsum, (__bf16*)cxb);

  GemmBatch3 fin = {};
  fin.d[0] = { cxb, wob, d_out, DMODEL, 0 };
  gemm_bt<64, 64, true>
      <<<dim3(DMODEL / 64, LQS / 64, 1), 256, 0, stream>>>(fin, DMODEL);
}